// Round 7
// baseline (756.229 us; speedup 1.0000x reference)
//
#include <hip/hip_runtime.h>
#include <cstdint>

// Problem constants (fixed by the reference setup_inputs)
#define BB    2
#define LL    2048
#define HH    8
#define EE    64
#define DIAG  64
#define RR    16         // output rows per block
#define WCAP  144        // staged window rows: jrel 0..143 <-> j = i0-64 .. i0+79
#define SK    68         // padded LDS row stride (floats) for K/V tile
#define PS    160        // padded prob-row stride (floats): 16 pad + 128 band + 16 pad
#define NT    256        // threads per block (4 waves)

// One 256-thread block per 16 consecutive rows of one (b,h). 2048 blocks.
//
// Structure = the verified-clean R2-era kernel (WRITE 271 MB / FETCH 12 MB):
// stage K -> sync -> softmax -> sync -> stage V -> sync -> store series -> PV.
// All series stores in ONE compact pass at the end, after all staging loads.
// The R3-era absolute-window prob layout + barrierless store reorder came
// with an (unexplained) 3x HBM traffic amplification — deliberately NOT used.
//
// Upgrades vs R2-era (LDS-domain only):
//  * Phase B GEMM: each K row read once per wave, reused across 4 rows.
//  * Phase E: each V float4 read once, reused across 4 rows.
//  * Padded prob rows (PS=160, index = band_slot + 15 - rowInTile... see below)
//    make every prob write unconditional; pads hold exact zeros.
__global__ __launch_bounds__(NT, 3) void anomaly_attn_kernel(
    const float* __restrict__ Q,   // [B, L, H, E]
    const float* __restrict__ K,   // [B, L, H, E]
    const float* __restrict__ V,   // [B, L, H, E]
    float* __restrict__ outV,      // [B, L, H, E]
    float* __restrict__ outS)      // [B, H, L, L]
{
    __shared__ float lds_kv[WCAP * SK];   // K tile, later reused as V tile (38.25 KB)
    __shared__ float lds_q[RR * EE];      // Q tile (4 KB)
    __shared__ float lds_sp[RR * PS];     // padded probs (10 KB)

    // XCD swizzle: contiguous row-blocks per XCD for L2 locality.
    const int bid  = blockIdx.x;
    const int gblk = (bid & 7) * 256 + (bid >> 3);   // [0, 2048)
    const int rb   = gblk & 127;
    const int h    = (gblk >> 7) & 7;
    const int b    = gblk >> 10;
    const int i0   = rb * RR;

    const int t    = threadIdx.x;
    const int wave = t >> 6;
    const int lane = t & 63;

    const size_t headOff = ((size_t)b * LL * HH + h) * EE;
    const int    rowStr  = HH * EE;   // 512 floats between sequence rows

    const int j0 = i0 - DIAG;         // jrel 0 <-> j = i0 - 64

    // ---- Phase A: stage Q tile + K window (rows clamped; masked in B) ----
    {
        const int qrow = t >> 4, qf = t & 15;
        *(float4*)(lds_q + qrow * EE + qf * 4) =
            *(const float4*)(Q + headOff + (size_t)(i0 + qrow) * rowStr + qf * 4);
        for (int idx = t; idx < WCAP * 16; idx += NT) {
            const int trow = idx >> 4, tf = idx & 15;
            int j = j0 + trow; j = j < 0 ? 0 : (j > LL - 1 ? LL - 1 : j);
            *(float4*)(lds_kv + trow * SK + tf * 4) =
                *(const float4*)(K + headOff + (size_t)j * rowStr + tf * 4);
        }
    }
    __syncthreads();

    // ---- Phase B: scores + softmax. Wave w owns rows 4w..4w+3.          ----
    // Lane owns window cols jrel in {lane, lane+64, 128+(lane&15)}; each K
    // row read ONCE per wave, reused across the wave's 4 output rows.
    // Prob layout: row rr stores band slot s (s = jrel-rr-1, 0..127) at
    // lds_sp[rr*PS + s + 16]. Writes below are UNCONDITIONAL: invalid lanes
    // write exact 0 into pad slots [15-rr,15] / [144-rr,158-rr] which Phase
    // D/E read as legitimate zeros. Covered index range [15-rr, 158-rr]
    // exactly equals everything D (16..143) and E ([15-rr,158-rr]) read.
    {
        float sa0=0.f,sa1=0.f,sa2=0.f,sa3=0.f;
        float sb0=0.f,sb1=0.f,sb2=0.f,sb3=0.f;
        float sc0=0.f,sc1=0.f,sc2=0.f,sc3=0.f;
        const float* ka = lds_kv + lane * SK;                // jrel = lane
        const float* kb = lds_kv + (lane + 64) * SK;         // jrel = 64+lane
        const float* kc = lds_kv + (128 + (lane & 15)) * SK; // jrel = 128+(lane&15)
        const float* qb = lds_q + wave * 4 * EE;
#pragma unroll
        for (int c = 0; c < 16; ++c) {
            const float4 A  = *(const float4*)(ka + c * 4);
            const float4 Bv = *(const float4*)(kb + c * 4);
            const float4 Cv = *(const float4*)(kc + c * 4);
            float4 q4;
            q4 = *(const float4*)(qb + 0 * EE + c * 4);
            sa0 += q4.x*A.x  + q4.y*A.y  + q4.z*A.z  + q4.w*A.w;
            sb0 += q4.x*Bv.x + q4.y*Bv.y + q4.z*Bv.z + q4.w*Bv.w;
            sc0 += q4.x*Cv.x + q4.y*Cv.y + q4.z*Cv.z + q4.w*Cv.w;
            q4 = *(const float4*)(qb + 1 * EE + c * 4);
            sa1 += q4.x*A.x  + q4.y*A.y  + q4.z*A.z  + q4.w*A.w;
            sb1 += q4.x*Bv.x + q4.y*Bv.y + q4.z*Bv.z + q4.w*Bv.w;
            sc1 += q4.x*Cv.x + q4.y*Cv.y + q4.z*Cv.z + q4.w*Cv.w;
            q4 = *(const float4*)(qb + 2 * EE + c * 4);
            sa2 += q4.x*A.x  + q4.y*A.y  + q4.z*A.z  + q4.w*A.w;
            sb2 += q4.x*Bv.x + q4.y*Bv.y + q4.z*Bv.z + q4.w*Bv.w;
            sc2 += q4.x*Cv.x + q4.y*Cv.y + q4.z*Cv.z + q4.w*Cv.w;
            q4 = *(const float4*)(qb + 3 * EE + c * 4);
            sa3 += q4.x*A.x  + q4.y*A.y  + q4.z*A.z  + q4.w*A.w;
            sb3 += q4.x*Bv.x + q4.y*Bv.y + q4.z*Bv.z + q4.w*Bv.w;
            sc3 += q4.x*Cv.x + q4.y*Cv.y + q4.z*Cv.z + q4.w*Cv.w;
        }

        const float scale = 0.125f;   // 1/sqrt(64)
        auto dorow = [&](int rr, float sA, float sB, float sC) {
            // validity of this lane's three window columns for row i0+rr:
            const bool va = (lane >= rr + 1) && (j0 + lane >= 0);
            const bool vb = (lane <= rr + 63) && (i0 + lane < LL);
            const bool vc = (lane < 16) && ((lane & 15) <= rr - 1) &&
                            (i0 + DIAG + (lane & 15) < LL);
            float As = va ? sA * scale : -3.0e38f;
            float Bs = vb ? sB * scale : -3.0e38f;
            float Cs = vc ? sC * scale : -3.0e38f;

            float m = fmaxf(As, fmaxf(Bs, Cs));
#pragma unroll
            for (int off = 1; off < 64; off <<= 1)
                m = fmaxf(m, __shfl_xor(m, off, 64));
            float pa = va ? __expf(As - m) : 0.f;
            float pb = vb ? __expf(Bs - m) : 0.f;
            float pc = vc ? __expf(Cs - m) : 0.f;
            float l = pa + pb + pc;
#pragma unroll
            for (int off = 1; off < 64; off <<= 1)
                l += __shfl_xor(l, off, 64);
            const float inv = 1.0f / l;
            float* prow = lds_sp + rr * PS;
            prow[lane - rr + 15]       = pa * inv;   // idx in [15-rr, 78-rr]
            prow[79 + lane - rr]       = pb * inv;   // idx in [79-rr, 142-rr]
            if (lane < 16)
                prow[143 + lane - rr]  = pc * inv;   // idx in [143-rr, 158-rr]
        };
        dorow(wave * 4 + 0, sa0, sb0, sc0);
        dorow(wave * 4 + 1, sa1, sb1, sc1);
        dorow(wave * 4 + 2, sa2, sb2, sc2);
        dorow(wave * 4 + 3, sa3, sb3, sc3);
    }
    __syncthreads();   // all waves done reading lds_kv (K)

    // ---- Phase A2: stage V window over lds_kv ----
    for (int idx = t; idx < WCAP * 16; idx += NT) {
        const int trow = idx >> 4, tf = idx & 15;
        int j = j0 + trow; j = j < 0 ? 0 : (j > LL - 1 ? LL - 1 : j);
        *(float4*)(lds_kv + trow * SK + tf * 4) =
            *(const float4*)(V + headOff + (size_t)j * rowStr + tf * 4);
    }
    __syncthreads();

    // ---- Phase D: stream full series rows (R2-era clamped-scalar form). ----
    // Band slot of column col for row i: d = col - (i-63); slot>=127 or the
    // clamp targets hold exact 0 (unconditional-write invariant above).
    for (int r4 = 0; r4 < 4; ++r4) {
        const int r = wave * 4 + r4;
        const int i = i0 + r;
        float4* srow4 = (float4*)(outS + (((size_t)(b * HH + h)) * LL + i) * LL);
        const int start = i - (DIAG - 1);
        const float* sp = lds_sp + r * PS + 16;   // sp[s] = prob at band slot s
#pragma unroll
        for (int k = 0; k < 8; ++k) {
            const int col4 = lane + k * 64;
            const int d0   = col4 * 4 - start;
            float4 v = make_float4(0.f, 0.f, 0.f, 0.f);
            {
                int i0c = d0     < 0 ? 0 : (d0     > 127 ? 127 : d0);
                int i1c = d0 + 1 < 0 ? 0 : (d0 + 1 > 127 ? 127 : d0 + 1);
                int i2c = d0 + 2 < 0 ? 0 : (d0 + 2 > 127 ? 127 : d0 + 2);
                int i3c = d0 + 3 < 0 ? 0 : (d0 + 3 > 127 ? 127 : d0 + 3);
                v.x = (d0     >= 0) ? sp[i0c] : 0.f;   // slot 127 holds 0
                v.y = (d0 + 1 >= 0) ? sp[i1c] : 0.f;
                v.z = (d0 + 2 >= 0) ? sp[i2c] : 0.f;
                v.w = (d0 + 3 >= 0) ? sp[i3c] : 0.f;
            }
            srow4[col4] = v;
        }
    }

    // ---- Phase E: O[rr,:] = sum_jrel P[rr][jrel] * V[jrel,:]            ----
    // Lane = (jsub = lane>>4, e4 = lane&15); each V float4 read once,
    // reused for the wave's 4 rows. P index: jrel - rr + 15 (pads = 0).
    {
        const int e4   = lane & 15;
        const int jsub = lane >> 4;
        const int rr0  = wave * 4;
        const float* p0 = lds_sp + (rr0 + 0) * PS + 15 - (rr0 + 0);
        const float* p1 = lds_sp + (rr0 + 1) * PS + 15 - (rr0 + 1);
        const float* p2 = lds_sp + (rr0 + 2) * PS + 15 - (rr0 + 2);
        const float* p3 = lds_sp + (rr0 + 3) * PS + 15 - (rr0 + 3);
        float4 a0 = make_float4(0,0,0,0), a1 = a0, a2 = a0, a3 = a0;
#pragma unroll
        for (int k = 0; k < WCAP / 4; ++k) {
            const int jrel = jsub + 4 * k;   // 0..143
            const float4 vv = *(const float4*)(lds_kv + jrel * SK + e4 * 4);
            const float w0 = p0[jrel];
            const float w1 = p1[jrel];
            const float w2 = p2[jrel];
            const float w3 = p3[jrel];
            a0.x += w0 * vv.x; a0.y += w0 * vv.y; a0.z += w0 * vv.z; a0.w += w0 * vv.w;
            a1.x += w1 * vv.x; a1.y += w1 * vv.y; a1.z += w1 * vv.z; a1.w += w1 * vv.w;
            a2.x += w2 * vv.x; a2.y += w2 * vv.y; a2.z += w2 * vv.z; a2.w += w2 * vv.w;
            a3.x += w3 * vv.x; a3.y += w3 * vv.y; a3.z += w3 * vv.z; a3.w += w3 * vv.w;
        }
#pragma unroll
        for (int off = 16; off <= 32; off <<= 1) {
            a0.x += __shfl_xor(a0.x, off, 64); a0.y += __shfl_xor(a0.y, off, 64);
            a0.z += __shfl_xor(a0.z, off, 64); a0.w += __shfl_xor(a0.w, off, 64);
            a1.x += __shfl_xor(a1.x, off, 64); a1.y += __shfl_xor(a1.y, off, 64);
            a1.z += __shfl_xor(a1.z, off, 64); a1.w += __shfl_xor(a1.w, off, 64);
            a2.x += __shfl_xor(a2.x, off, 64); a2.y += __shfl_xor(a2.y, off, 64);
            a2.z += __shfl_xor(a2.z, off, 64); a2.w += __shfl_xor(a2.w, off, 64);
            a3.x += __shfl_xor(a3.x, off, 64); a3.y += __shfl_xor(a3.y, off, 64);
            a3.z += __shfl_xor(a3.z, off, 64); a3.w += __shfl_xor(a3.w, off, 64);
        }
        if (lane < 16) {
            float4* o0 = (float4*)(outV + headOff + (size_t)(i0 + rr0 + 0) * rowStr);
            float4* o1 = (float4*)(outV + headOff + (size_t)(i0 + rr0 + 1) * rowStr);
            float4* o2 = (float4*)(outV + headOff + (size_t)(i0 + rr0 + 2) * rowStr);
            float4* o3 = (float4*)(outV + headOff + (size_t)(i0 + rr0 + 3) * rowStr);
            o0[e4] = a0; o1[e4] = a1; o2[e4] = a2; o3[e4] = a3;
        }
    }
}

extern "C" void kernel_launch(void* const* d_in, const int* in_sizes, int n_in,
                              void* d_out, int out_size, void* d_ws, size_t ws_size,
                              hipStream_t stream) {
    const float* Q = (const float*)d_in[0];
    const float* K = (const float*)d_in[1];
    const float* V = (const float*)d_in[2];
    // d_in[3] = sigma (unused by reference), d_in[4] = attn_mask (unused)

    float* outV = (float*)d_out;                                   // [B,L,H,E]
    float* outS = (float*)d_out + (size_t)BB * LL * HH * EE;       // [B,H,L,L]

    const int grid = (BB * HH * LL) / RR;  // 2048 blocks
    anomaly_attn_kernel<<<grid, NT, 0, stream>>>(Q, K, V, outV, outS);
}

// Round 8
// 344.222 us; speedup vs baseline: 2.1969x; 2.1969x over previous
//
#include <hip/hip_runtime.h>
#include <cstdint>

// Problem constants (fixed by the reference setup_inputs)
#define BB    2
#define LL    2048
#define HH    8
#define EE    64
#define DIAG  64
#define RR    16         // output rows per block
#define WCAP  144        // staged window rows: jrel 0..143 <-> j = i0-63 .. i0+80
#define SK    68         // padded LDS row stride (floats) for K/V tile
#define PS    160        // padded prob-row stride: 16 pad | 128 band slots | 16 pad
#define NT    256        // threads per block (4 waves)

// One 256-thread block per 16 consecutive rows of one (b,h). 2048 blocks.
//
// SPILL LESSON (R4-R7): any Phase-B shape holding 12 accumulators live
// (c-outer loop) spills to scratch => +~500MB HBM write / +~600MB fetch,
// deterministic, VGPR_Count pinned at 84. Phase B below is the proven-clean
// R3 shape: r-outer, TWO live accumulators, K pointers recomputed per row.
// WRITE LESSON (R4): every outS line written exactly once, one compact pass.
//
// Single controlled delta vs R3: Phase E reads each V float4 ONCE and
// broadcasts 4 scalar probs (constant-offset LDS reads) -> ~92 fewer
// ds_read_b128 per wave. Enabled by padded prob rows (zero-initialized
// wave-locally; band slot s of row r lives at lds_sp[r*PS + 16 + s]).
__global__ __launch_bounds__(NT, 3) void anomaly_attn_kernel(
    const float* __restrict__ Q,   // [B, L, H, E]
    const float* __restrict__ K,   // [B, L, H, E]
    const float* __restrict__ V,   // [B, L, H, E]
    float* __restrict__ outV,      // [B, L, H, E]
    float* __restrict__ outS)      // [B, H, L, L]
{
    __shared__ float lds_kv[WCAP * SK];   // K tile, later reused as V tile (39.2 KB)
    __shared__ float lds_q[RR * EE];      // Q tile (4 KB)
    __shared__ float lds_sp[RR * PS];     // padded probs (10 KB)

    // XCD swizzle: contiguous row-blocks per XCD for L2 locality.
    const int bid  = blockIdx.x;
    const int gblk = (bid & 7) * 256 + (bid >> 3);   // [0, 2048)
    const int rb   = gblk & 127;
    const int h    = (gblk >> 7) & 7;
    const int b    = gblk >> 10;
    const int i0   = rb * RR;

    const int t    = threadIdx.x;
    const int wave = t >> 6;
    const int lane = t & 63;

    const size_t headOff = ((size_t)b * LL * HH + h) * EE;
    const int    rowStr  = HH * EE;   // 512 floats between sequence rows

    const int j0 = i0 - (DIAG - 1);   // jrel 0 <-> j = i0 - 63

    // ---- Phase P: zero this wave's 4 prob rows (wave-local, no barrier). ----
    {
        const float4 z4 = make_float4(0.f, 0.f, 0.f, 0.f);
        float4* zp = (float4*)(lds_sp + wave * 4 * PS);
        for (int z = lane; z < 160; z += 64) zp[z] = z4;   // 4*PS/4 = 160 f4
    }

    // ---- Phase A: stage Q tile + K window (rows clamped; masked in B) ----
    {
        const int qrow = t >> 4, qf = t & 15;
        *(float4*)(lds_q + qrow * EE + qf * 4) =
            *(const float4*)(Q + headOff + (size_t)(i0 + qrow) * rowStr + qf * 4);
        for (int idx = t; idx < WCAP * 16; idx += NT) {
            const int trow = idx >> 4, tf = idx & 15;
            int j = j0 + trow; j = j < 0 ? 0 : (j > LL - 1 ? LL - 1 : j);
            *(float4*)(lds_kv + trow * SK + tf * 4) =
                *(const float4*)(K + headOff + (size_t)j * rowStr + tf * 4);
        }
    }
    __syncthreads();

    // ---- Phase B: scores + softmax. R3 SHAPE: r-outer, 2 live accs.     ----
    // Wave w owns rows 4w..4w+3. For row r, lane owns band slots
    // {lane, lane+64} (jrel = r+lane, r+lane+64). Slot 127 is masked to 0.
    const float scale = 0.125f;   // 1/sqrt(64)
    for (int r4 = 0; r4 < 4; ++r4) {
        const int r = wave * 4 + r4;
        const int i = i0 + r;
        const float* qrow = lds_q + r * EE;
        const float* k1   = lds_kv + (r + lane) * SK;        // slot = lane
        const float* k2   = k1 + 64 * SK;                    // slot = lane+64
        float s1 = 0.f, s2 = 0.f;
#pragma unroll
        for (int c = 0; c < 16; ++c) {
            const float4 q4 = *(const float4*)(qrow + c * 4);   // broadcast
            const float4 a4 = *(const float4*)(k1 + c * 4);
            const float4 b4 = *(const float4*)(k2 + c * 4);
            s1 += q4.x * a4.x + q4.y * a4.y + q4.z * a4.z + q4.w * a4.w;
            s2 += q4.x * b4.x + q4.y * b4.y + q4.z * b4.z + q4.w * b4.w;
        }
        const int  slot2 = lane + 64;
        const bool v1 = (i - (DIAG - 1) + lane) >= 0;                  // j1 >= 0
        const bool v2 = (slot2 < 2 * DIAG - 1) && (i - (DIAG - 1) + slot2 < LL);
        float sc1 = v1 ? s1 * scale : -3.0e38f;
        float sc2 = v2 ? s2 * scale : -3.0e38f;

        float m = fmaxf(sc1, sc2);
#pragma unroll
        for (int off = 1; off < 64; off <<= 1)
            m = fmaxf(m, __shfl_xor(m, off, 64));
        float p1 = v1 ? __expf(sc1 - m) : 0.f;
        float p2 = v2 ? __expf(sc2 - m) : 0.f;
        float l = p1 + p2;
#pragma unroll
        for (int off = 1; off < 64; off <<= 1)
            l += __shfl_xor(l, off, 64);
        const float inv = 1.0f / l;
        float* prow = lds_sp + r * PS;
        prow[16 + lane]      = p1 * inv;   // band slot lane
        prow[80 + lane]      = p2 * inv;   // band slot lane+64 (127 -> exact 0)
    }
    __syncthreads();   // all waves done reading lds_kv (K)

    // ---- Phase A2: stage V window over lds_kv ----
    for (int idx = t; idx < WCAP * 16; idx += NT) {
        const int trow = idx >> 4, tf = idx & 15;
        int j = j0 + trow; j = j < 0 ? 0 : (j > LL - 1 ? LL - 1 : j);
        *(float4*)(lds_kv + trow * SK + tf * 4) =
            *(const float4*)(V + headOff + (size_t)j * rowStr + tf * 4);
    }
    __syncthreads();

    // ---- Phase D: stream full series rows (R3 clamped-scalar form).     ----
    for (int r4 = 0; r4 < 4; ++r4) {
        const int r = wave * 4 + r4;
        const int i = i0 + r;
        float4* srow4 = (float4*)(outS + (((size_t)(b * HH + h)) * LL + i) * LL);
        const int start = i - (DIAG - 1);
        const float* sp = lds_sp + r * PS + 16;   // sp[s] = prob at band slot s
#pragma unroll
        for (int k = 0; k < 8; ++k) {
            const int col4 = lane + k * 64;
            const int d0   = col4 * 4 - start;
            float4 v;
            int i0c = d0     < 0 ? 0 : (d0     > 127 ? 127 : d0);
            int i1c = d0 + 1 < 0 ? 0 : (d0 + 1 > 127 ? 127 : d0 + 1);
            int i2c = d0 + 2 < 0 ? 0 : (d0 + 2 > 127 ? 127 : d0 + 2);
            int i3c = d0 + 3 < 0 ? 0 : (d0 + 3 > 127 ? 127 : d0 + 3);
            v.x = (d0     >= 0) ? sp[i0c] : 0.f;   // slot 127 holds 0
            v.y = (d0 + 1 >= 0) ? sp[i1c] : 0.f;
            v.z = (d0 + 2 >= 0) ? sp[i2c] : 0.f;
            v.w = (d0 + 3 >= 0) ? sp[i3c] : 0.f;
            srow4[col4] = v;
        }
    }

    // ---- Phase E (the one delta): each V float4 read ONCE, reused for   ----
    // the wave's 4 rows via broadcast prob reads at constant offsets.
    // Row r, window col jrel: band slot s = jrel - r; flat prob index
    // r*PS + 16 + jrel - r = r*(PS-1) + jrel + 16.
    {
        const int e4   = lane & 15;
        const int jsub = lane >> 4;
        const int rr0  = wave * 4;
        const float* pbase = lds_sp + rr0 * (PS - 1) + 16;   // + dr*(PS-1) + jrel
        float4 a0 = make_float4(0,0,0,0), a1 = a0, a2 = a0, a3 = a0;
#pragma unroll
        for (int k = 0; k < WCAP / 4; ++k) {
            const int jrel = jsub + 4 * k;   // 0..143
            const float4 vv = *(const float4*)(lds_kv + jrel * SK + e4 * 4);
            const float w0 = pbase[jrel];                    // pads/invalid -> 0
            const float w1 = pbase[(PS - 1) + jrel];
            const float w2 = pbase[2 * (PS - 1) + jrel];
            const float w3 = pbase[3 * (PS - 1) + jrel];
            a0.x += w0 * vv.x; a0.y += w0 * vv.y; a0.z += w0 * vv.z; a0.w += w0 * vv.w;
            a1.x += w1 * vv.x; a1.y += w1 * vv.y; a1.z += w1 * vv.z; a1.w += w1 * vv.w;
            a2.x += w2 * vv.x; a2.y += w2 * vv.y; a2.z += w2 * vv.z; a2.w += w2 * vv.w;
            a3.x += w3 * vv.x; a3.y += w3 * vv.y; a3.z += w3 * vv.z; a3.w += w3 * vv.w;
        }
#pragma unroll
        for (int off = 16; off <= 32; off <<= 1) {
            a0.x += __shfl_xor(a0.x, off, 64); a0.y += __shfl_xor(a0.y, off, 64);
            a0.z += __shfl_xor(a0.z, off, 64); a0.w += __shfl_xor(a0.w, off, 64);
            a1.x += __shfl_xor(a1.x, off, 64); a1.y += __shfl_xor(a1.y, off, 64);
            a1.z += __shfl_xor(a1.z, off, 64); a1.w += __shfl_xor(a1.w, off, 64);
            a2.x += __shfl_xor(a2.x, off, 64); a2.y += __shfl_xor(a2.y, off, 64);
            a2.z += __shfl_xor(a2.z, off, 64); a2.w += __shfl_xor(a2.w, off, 64);
            a3.x += __shfl_xor(a3.x, off, 64); a3.y += __shfl_xor(a3.y, off, 64);
            a3.z += __shfl_xor(a3.z, off, 64); a3.w += __shfl_xor(a3.w, off, 64);
        }
        if (lane < 16) {
            float4* o0 = (float4*)(outV + headOff + (size_t)(i0 + rr0 + 0) * rowStr);
            float4* o1 = (float4*)(outV + headOff + (size_t)(i0 + rr0 + 1) * rowStr);
            float4* o2 = (float4*)(outV + headOff + (size_t)(i0 + rr0 + 2) * rowStr);
            float4* o3 = (float4*)(outV + headOff + (size_t)(i0 + rr0 + 3) * rowStr);
            o0[e4] = a0; o1[e4] = a1; o2[e4] = a2; o3[e4] = a3;
        }
    }
}

extern "C" void kernel_launch(void* const* d_in, const int* in_sizes, int n_in,
                              void* d_out, int out_size, void* d_ws, size_t ws_size,
                              hipStream_t stream) {
    const float* Q = (const float*)d_in[0];
    const float* K = (const float*)d_in[1];
    const float* V = (const float*)d_in[2];
    // d_in[3] = sigma (unused by reference), d_in[4] = attn_mask (unused)

    float* outV = (float*)d_out;                                   // [B,L,H,E]
    float* outS = (float*)d_out + (size_t)BB * LL * HH * EE;       // [B,H,L,L]

    const int grid = (BB * HH * LL) / RR;  // 2048 blocks
    anomaly_attn_kernel<<<grid, NT, 0, stream>>>(Q, K, V, outV, outS);
}

// Round 9
// 336.037 us; speedup vs baseline: 2.2504x; 1.0244x over previous
//
#include <hip/hip_runtime.h>
#include <cstdint>

// Problem constants (fixed by the reference setup_inputs)
#define BB    2
#define LL    2048
#define HH    8
#define EE    64
#define DIAG  64
#define RR    16         // output rows per block
#define WCAP  144        // staged window rows: jrel 0..143 <-> j = i0-64 .. i0+79
#define SK    68         // padded LDS row stride (floats) for K/V tile
#define PS    148        // prob-row stride (floats), 4-aligned; jrel-absolute layout
#define NT    256        // threads per block (4 waves)

// One 256-thread block per 16 consecutive rows of one (b,h). 2048 blocks.
//
// SPILL LESSON (R4-R7): c-outer Phase-B holding 12 accumulators live spills
// to scratch (=> +500MB write/+600MB fetch HBM, deterministic). Phase B here
// uses 2-row passes: 4 live accumulators + 4 float4 temps only.
// WRITE LESSON (R4): every outS line written exactly once, one compact pass,
// phase order identical to the proven-clean R8: A,sync,B,sync,A2,sync,D,E.
//
// jrel convention (absolute window): jrel = j - (i0 - 64), jrel in [0,144).
// Window start i0-64 is 4-aligned => Phase D reads probs as ALIGNED float4.
// Row r (i = i0+r) band: jrel in [r+1, r+127]; all other slots hold exact 0.
__global__ __launch_bounds__(NT, 3) void anomaly_attn_kernel(
    const float* __restrict__ Q,   // [B, L, H, E]
    const float* __restrict__ K,   // [B, L, H, E]
    const float* __restrict__ V,   // [B, L, H, E]
    float* __restrict__ outV,      // [B, L, H, E]
    float* __restrict__ outS)      // [B, H, L, L]
{
    __shared__ float lds_kv[WCAP * SK];   // K tile, later reused as V tile (38.25 KB)
    __shared__ float lds_q[RR * EE];      // Q tile (4 KB)
    __shared__ float lds_sp[RR * PS];     // probs, jrel-absolute rows (9.25 KB)

    // XCD swizzle: contiguous row-blocks per XCD for L2 locality.
    const int bid  = blockIdx.x;
    const int gblk = (bid & 7) * 256 + (bid >> 3);   // [0, 2048)
    const int rb   = gblk & 127;
    const int h    = (gblk >> 7) & 7;
    const int b    = gblk >> 10;
    const int i0   = rb * RR;

    const int t    = threadIdx.x;
    const int wave = t >> 6;
    const int lane = t & 63;

    const size_t headOff = ((size_t)b * LL * HH + h) * EE;
    const int    rowStr  = HH * EE;   // 512 floats between sequence rows

    const int j0  = i0 - 64;          // jrel 0 <-> j = i0 - 64 (4-aligned)
    const int j04 = j0 >> 2;

    // ---- Phase P: zero this wave's 4 prob rows (wave-local, no barrier) ----
    {
        const float4 z4 = make_float4(0.f, 0.f, 0.f, 0.f);
        float4* zp = (float4*)(lds_sp + wave * 4 * PS);
        for (int z = lane; z < PS; z += 64) zp[z] = z4;   // 4*PS/4 = PS float4s
    }

    // ---- Phase A: stage Q tile + K window (rows clamped; masked in B) ----
    {
        const int qrow = t >> 4, qf = t & 15;
        *(float4*)(lds_q + qrow * EE + qf * 4) =
            *(const float4*)(Q + headOff + (size_t)(i0 + qrow) * rowStr + qf * 4);
        for (int idx = t; idx < WCAP * 16; idx += NT) {
            const int trow = idx >> 4, tf = idx & 15;
            int j = j0 + trow; j = j < 0 ? 0 : (j > LL - 1 ? LL - 1 : j);
            *(float4*)(lds_kv + trow * SK + tf * 4) =
                *(const float4*)(K + headOff + (size_t)j * rowStr + tf * 4);
        }
    }
    __syncthreads();

    // ---- Phase B: scores + softmax, 2-row passes sharing K reads.       ----
    // Pass p handles rows rA = wave*4+2p, rB = rA+1. Lane owns fixed window
    // columns jrelA = rA+1+lane, jrelB = rA+65+lane; each K float4 is read
    // once and used for BOTH rows (q differs). 4 live accumulators only.
    const float scale = 0.125f;   // 1/sqrt(64)
#pragma unroll
    for (int p = 0; p < 2; ++p) {
        const int rA = wave * 4 + 2 * p;
        const int rB = rA + 1;
        const int jrelA = rA + 1 + lane;           // [rA+1, rA+64]
        const int jrelB = rA + 65 + lane;          // [rA+65, rA+128]
        const float* k1 = lds_kv + jrelA * SK;
        const float* k2 = lds_kv + jrelB * SK;
        const float* qA = lds_q + rA * EE;
        const float* qB = lds_q + rB * EE;
        float sA1 = 0.f, sA2 = 0.f, sB1 = 0.f, sB2 = 0.f;
#pragma unroll
        for (int c = 0; c < 16; ++c) {
            const float4 a4  = *(const float4*)(k1 + c * 4);
            const float4 b4  = *(const float4*)(k2 + c * 4);
            const float4 qa4 = *(const float4*)(qA + c * 4);   // broadcast
            const float4 qb4 = *(const float4*)(qB + c * 4);   // broadcast
            sA1 += qa4.x*a4.x + qa4.y*a4.y + qa4.z*a4.z + qa4.w*a4.w;
            sA2 += qa4.x*b4.x + qa4.y*b4.y + qa4.z*b4.z + qa4.w*b4.w;
            sB1 += qb4.x*a4.x + qb4.y*a4.y + qb4.z*a4.z + qb4.w*a4.w;
            sB2 += qb4.x*b4.x + qb4.y*b4.y + qb4.z*b4.z + qb4.w*b4.w;
        }
        const int jA = j0 + jrelA;   // global column of jrelA
        const int jB = j0 + jrelB;
        // Row rA: slotA = lane in [0,63]; slotB = 64+lane in [64,127]
        const bool vA1 = (jA >= 0);                         // slot<=63 => j<=iA<LL
        const bool vA2 = (lane <= 62) && (jB < LL);         // slot 127 masked
        // Row rB: slotA = lane-1; slotB = 63+lane in [63,126]
        const bool vB1 = (lane >= 1) && (jA >= 0);
        const bool vB2 = (jB < LL);
        float eA1 = vA1 ? sA1 * scale : -3.0e38f;
        float eA2 = vA2 ? sA2 * scale : -3.0e38f;
        float eB1 = vB1 ? sB1 * scale : -3.0e38f;
        float eB2 = vB2 ? sB2 * scale : -3.0e38f;

        float mA = fmaxf(eA1, eA2);
        float mB = fmaxf(eB1, eB2);
#pragma unroll
        for (int off = 1; off < 64; off <<= 1) {
            mA = fmaxf(mA, __shfl_xor(mA, off, 64));
            mB = fmaxf(mB, __shfl_xor(mB, off, 64));
        }
        float pA1 = vA1 ? __expf(eA1 - mA) : 0.f;
        float pA2 = vA2 ? __expf(eA2 - mA) : 0.f;
        float pB1 = vB1 ? __expf(eB1 - mB) : 0.f;
        float pB2 = vB2 ? __expf(eB2 - mB) : 0.f;
        float lA = pA1 + pA2;
        float lB = pB1 + pB2;
#pragma unroll
        for (int off = 1; off < 64; off <<= 1) {
            lA += __shfl_xor(lA, off, 64);
            lB += __shfl_xor(lB, off, 64);
        }
        const float invA = 1.0f / lA;
        const float invB = 1.0f / lB;
        lds_sp[rA * PS + jrelA] = pA1 * invA;   // invalid lanes deposit exact 0
        lds_sp[rA * PS + jrelB] = pA2 * invA;
        lds_sp[rB * PS + jrelA] = pB1 * invB;
        lds_sp[rB * PS + jrelB] = pB2 * invB;
    }
    __syncthreads();   // all waves done reading lds_kv (K)

    // ---- Phase A2: stage V window over lds_kv ----
    for (int idx = t; idx < WCAP * 16; idx += NT) {
        const int trow = idx >> 4, tf = idx & 15;
        int j = j0 + trow; j = j < 0 ? 0 : (j > LL - 1 ? LL - 1 : j);
        *(float4*)(lds_kv + trow * SK + tf * 4) =
            *(const float4*)(V + headOff + (size_t)j * rowStr + tf * 4);
    }
    __syncthreads();

    // ---- Phase D: stream full series rows; window = ALIGNED f4 copies.  ----
    // col4 in [wstart4,wend4) reads lds_sp f4 index (col4 - j04); else zero.
    {
        const int wstart4 = j04 < 0 ? 0 : j04;
        int wend4 = j04 + 36; if (wend4 > LL / 4) wend4 = LL / 4;
        for (int r4 = 0; r4 < 4; ++r4) {
            const int r = wave * 4 + r4;
            const int i = i0 + r;
            float4* srow4 = (float4*)(outS + (((size_t)(b * HH + h)) * LL + i) * LL);
            const float4* sp4 = (const float4*)(lds_sp + r * PS);
#pragma unroll
            for (int k = 0; k < 8; ++k) {
                const int col4 = lane + k * 64;
                float4 v = make_float4(0.f, 0.f, 0.f, 0.f);
                if (col4 >= wstart4 && col4 < wend4)
                    v = sp4[col4 - j04];
                srow4[col4] = v;
            }
        }
    }

    // ---- Phase E: O[r,:] = sum_jrel P[r][jrel] * V[jrel,:]              ----
    // Lane = (jsub = lane>>4, e4 = lane&15); each V float4 read once,
    // reused for the wave's 4 rows via broadcast prob reads (absolute jrel).
    {
        const int e4   = lane & 15;
        const int jsub = lane >> 4;
        const int rr0  = wave * 4;
        const float* pbase = lds_sp + rr0 * PS;
        float4 a0 = make_float4(0,0,0,0), a1 = a0, a2 = a0, a3 = a0;
#pragma unroll
        for (int k = 0; k < WCAP / 4; ++k) {
            const int jrel = jsub + 4 * k;   // 0..143
            const float4 vv = *(const float4*)(lds_kv + jrel * SK + e4 * 4);
            const float w0 = pbase[jrel];                    // pads/invalid -> 0
            const float w1 = pbase[PS + jrel];
            const float w2 = pbase[2 * PS + jrel];
            const float w3 = pbase[3 * PS + jrel];
            a0.x += w0 * vv.x; a0.y += w0 * vv.y; a0.z += w0 * vv.z; a0.w += w0 * vv.w;
            a1.x += w1 * vv.x; a1.y += w1 * vv.y; a1.z += w1 * vv.z; a1.w += w1 * vv.w;
            a2.x += w2 * vv.x; a2.y += w2 * vv.y; a2.z += w2 * vv.z; a2.w += w2 * vv.w;
            a3.x += w3 * vv.x; a3.y += w3 * vv.y; a3.z += w3 * vv.z; a3.w += w3 * vv.w;
        }
#pragma unroll
        for (int off = 16; off <= 32; off <<= 1) {
            a0.x += __shfl_xor(a0.x, off, 64); a0.y += __shfl_xor(a0.y, off, 64);
            a0.z += __shfl_xor(a0.z, off, 64); a0.w += __shfl_xor(a0.w, off, 64);
            a1.x += __shfl_xor(a1.x, off, 64); a1.y += __shfl_xor(a1.y, off, 64);
            a1.z += __shfl_xor(a1.z, off, 64); a1.w += __shfl_xor(a1.w, off, 64);
            a2.x += __shfl_xor(a2.x, off, 64); a2.y += __shfl_xor(a2.y, off, 64);
            a2.z += __shfl_xor(a2.z, off, 64); a2.w += __shfl_xor(a2.w, off, 64);
            a3.x += __shfl_xor(a3.x, off, 64); a3.y += __shfl_xor(a3.y, off, 64);
            a3.z += __shfl_xor(a3.z, off, 64); a3.w += __shfl_xor(a3.w, off, 64);
        }
        if (lane < 16) {
            float4* o0 = (float4*)(outV + headOff + (size_t)(i0 + rr0 + 0) * rowStr);
            float4* o1 = (float4*)(outV + headOff + (size_t)(i0 + rr0 + 1) * rowStr);
            float4* o2 = (float4*)(outV + headOff + (size_t)(i0 + rr0 + 2) * rowStr);
            float4* o3 = (float4*)(outV + headOff + (size_t)(i0 + rr0 + 3) * rowStr);
            o0[e4] = a0; o1[e4] = a1; o2[e4] = a2; o3[e4] = a3;
        }
    }
}

extern "C" void kernel_launch(void* const* d_in, const int* in_sizes, int n_in,
                              void* d_out, int out_size, void* d_ws, size_t ws_size,
                              hipStream_t stream) {
    const float* Q = (const float*)d_in[0];
    const float* K = (const float*)d_in[1];
    const float* V = (const float*)d_in[2];
    // d_in[3] = sigma (unused by reference), d_in[4] = attn_mask (unused)

    float* outV = (float*)d_out;                                   // [B,L,H,E]
    float* outS = (float*)d_out + (size_t)BB * LL * HH * EE;       // [B,H,L,L]

    const int grid = (BB * HH * LL) / RR;  // 2048 blocks
    anomaly_attn_kernel<<<grid, NT, 0, stream>>>(Q, K, V, outV, outS);
}